// Round 6
// baseline (2418.067 us; speedup 1.0000x reference)
//
#include <hip/hip_runtime.h>
#include <hip/hip_bf16.h>

#define B_SZ 1024
#define H_DIM 1536
#define H3 (3*H_DIM)
#define LMAX 32
#define TEMP_INV 20.0f
#define GH_BLOCKS 192

typedef __attribute__((ext_vector_type(4))) float f32x4;
typedef __attribute__((ext_vector_type(8))) short short8;
typedef unsigned short u16;
typedef unsigned int u32;

__device__ __forceinline__ u16 f2bf(float f){
  union { float f; u32 u; } v; v.f = f;
  u32 r = (v.u + 0x7FFFu + ((v.u >> 16) & 1u)) >> 16;
  return (u16)r;
}
__device__ __forceinline__ u32 pack2(float lo, float hi){
  return (u32)f2bf(lo) | ((u32)f2bf(hi) << 16);
}
__device__ __forceinline__ float bf2f(u16 b){
  union { u32 u; float f; } v; v.u = ((u32)b) << 16; return v.f;
}
__device__ __forceinline__ float sigm(float x){ return 1.f / (1.f + __expf(-x)); }

__device__ __forceinline__ void gload_lds16(const void* g, void* l){
  __builtin_amdgcn_global_load_lds(
      (const __attribute__((address_space(1))) void*)g,
      (__attribute__((address_space(3))) void*)l, 16, 0, 0);
}

// ---------------- sort: rank (desc by len, stable), cnt_t, tstart, rowmap ----
__global__ void sort_kernel(const int* __restrict__ lens, int* __restrict__ rank,
                            int* __restrict__ cnt_arr, int* __restrict__ tstart,
                            int* __restrict__ rowmap)
{
  __shared__ int sl[B_SZ];
  __shared__ int soff[B_SZ];
  __shared__ int sts[LMAX];
  int i = threadIdx.x;
  int li = lens[i];
  sl[i] = li; soff[i] = li;
  __syncthreads();
  for (int off = 1; off < B_SZ; off <<= 1){
    int v = (i >= off) ? soff[i-off] : 0;
    __syncthreads();
    soff[i] += v;
    __syncthreads();
  }
  int myoff = soff[i] - li;                 // exclusive cumsum (original order)
  int r = 0;
  for (int j = 0; j < B_SZ; ++j){
    int lj = sl[j];
    r += (lj > li) || (lj == li && j < i);  // rank: desc len, stable
  }
  rank[i] = r;
  if (i < LMAX){
    int c = 0;
    for (int j = 0; j < B_SZ; ++j) c += (sl[j] > i);
    cnt_arr[i] = c;
  }
  __syncthreads();
  if (i == 0){
    // cnt values live in cnt_arr (global, same CU) — recompute locally to LDS
    int acc = 0;
    for (int t = 0; t < LMAX; ++t){
      int c = 0;
      // cheap: reuse sl
      for (int j = 0; j < B_SZ; ++j) c += (sl[j] > t);
      sts[t] = acc; tstart[t] = acc; acc += c;
    }
  }
  __syncthreads();
  for (int t = 0; t < li; ++t)
    rowmap[myoff + t] = sts[t] + r;         // packed (t, rank) position
}

// ---------------- prep: weights/k -> bf16, hs0[rank[i]] = bf16(q[i]) --------
__global__ void prep_kernel(const float* __restrict__ wih, const float* __restrict__ whh,
                            const float* __restrict__ kemb, const float* __restrict__ qemb,
                            const int* __restrict__ rank,
                            u16* __restrict__ wih_bf, u16* __restrict__ whh_bf,
                            u16* __restrict__ k_bf, u16* __restrict__ h0)
{
  size_t o = ((size_t)blockIdx.x * 256 + threadIdx.x) * 8;
  if (o < (size_t)H3 * H_DIM) {
    float4 a0 = *(const float4*)(wih + o), a1 = *(const float4*)(wih + o + 4);
    *(uint4*)(wih_bf + o) = make_uint4(pack2(a0.x,a0.y), pack2(a0.z,a0.w),
                                       pack2(a1.x,a1.y), pack2(a1.z,a1.w));
    float4 b0 = *(const float4*)(whh + o), b1 = *(const float4*)(whh + o + 4);
    *(uint4*)(whh_bf + o) = make_uint4(pack2(b0.x,b0.y), pack2(b0.z,b0.w),
                                       pack2(b1.x,b1.y), pack2(b1.z,b1.w));
  }
  if (o < (size_t)B_SZ * H_DIM) {
    float4 k0 = *(const float4*)(kemb + o), k1 = *(const float4*)(kemb + o + 4);
    *(uint4*)(k_bf + o) = make_uint4(pack2(k0.x,k0.y), pack2(k0.z,k0.w),
                                     pack2(k1.x,k1.y), pack2(k1.z,k1.w));
    int i = (int)(o / H_DIM), col = (int)(o % H_DIM);
    float4 q0 = *(const float4*)(qemb + o), q1 = *(const float4*)(qemb + o + 4);
    *(uint4*)(h0 + (size_t)rank[i] * H_DIM + col) =
        make_uint4(pack2(q0.x,q0.y), pack2(q0.z,q0.w),
                   pack2(q1.x,q1.y), pack2(q1.z,q1.w));
  }
}

// ------- convx: f32 -> bf16, scattered ONCE into (t, rank)-packed order -----
__global__ void convx_kernel(const float* __restrict__ x, const int* __restrict__ rowmap,
                             u16* __restrict__ xt, int total){
  size_t o = ((size_t)blockIdx.x * 256 + threadIdx.x) * 8;
  int row = (int)(o / H_DIM), col = (int)(o % H_DIM);
  if (row < total) {
    float4 a0 = *(const float4*)(x + o), a1 = *(const float4*)(x + o + 4);
    *(uint4*)(xt + (size_t)rowmap[row] * H_DIM + col) =
        make_uint4(pack2(a0.x,a0.y), pack2(a0.z,a0.w),
                   pack2(a1.x,a1.y), pack2(a1.z,a1.w));
  } else {
    *(uint4*)(xt + o) = make_uint4(0,0,0,0);   // zero padding rows
  }
}

// ---------------- GI = xt @ W_ih^T + b_ih  (128x128 tile, BK=64) ------------
__global__ __launch_bounds__(256, 2) void gi_gemm_kernel(
    const u16* __restrict__ x_bf, const u16* __restrict__ wih_bf,
    const float* __restrict__ b_ih, u16* __restrict__ gi, int nblk_m)
{
  int nblk = nblk_m * 36;
  int id = blockIdx.x;
  int q8 = nblk >> 3, r8 = nblk & 7;
  int xcd = id & 7, off = id >> 3;
  int swz = (xcd < r8) ? (xcd * (q8 + 1) + off) : (r8 * (q8 + 1) + (xcd - r8) * q8 + off);
  int bx = swz / 36, by = swz % 36;

  __shared__ u16 lds[2 * 128 * 64];
  char* ldsb = (char*)lds;
  int tid = threadIdx.x, wid = tid >> 6, lane = tid & 63;
  int wm = wid >> 1, wn = wid & 1;
  int lrow = lane & 15, lkh = lane >> 4;
  f32x4 acc[4][4] = {};

  for (int kt = 0; kt < 24; ++kt) {
    int k0 = kt * 64;
    #pragma unroll
    for (int it = 0; it < 8; ++it) {
      int cb = it * 256 + wid * 64;
      int c  = cb + lane;
      int isB = c >> 10;
      int cc  = c & 1023;
      int row = cc >> 3, slot = cc & 7;
      const u16* src = isB ? (wih_bf + (size_t)(by * 128 + row) * H_DIM)
                           : (x_bf  + (size_t)(bx * 128 + row) * H_DIM);
      src += k0 + ((slot ^ (row & 7)) << 3);
      gload_lds16(src, ldsb + (size_t)cb * 16);
    }
    __syncthreads();
    #pragma unroll
    for (int qq = 0; qq < 2; ++qq) {
      short8 a[4], b[4];
      int slot = qq * 4 + lkh;
      #pragma unroll
      for (int m = 0; m < 4; ++m) {
        int row = wm * 64 + m * 16 + lrow;
        a[m] = *(const short8*)(ldsb + row * 128 + ((slot ^ (row & 7)) << 4));
      }
      #pragma unroll
      for (int n = 0; n < 4; ++n) {
        int row = wn * 64 + n * 16 + lrow;
        b[n] = *(const short8*)(ldsb + 16384 + row * 128 + ((slot ^ (row & 7)) << 4));
      }
      #pragma unroll
      for (int m = 0; m < 4; ++m)
        #pragma unroll
        for (int n = 0; n < 4; ++n)
          acc[m][n] = __builtin_amdgcn_mfma_f32_16x16x32_bf16(a[m], b[n], acc[m][n], 0,0,0);
    }
    __syncthreads();
  }
  #pragma unroll
  for (int n = 0; n < 4; ++n) {
    int j = by * 128 + wn * 64 + n * 16 + lrow;
    float bias = b_ih[j];
    #pragma unroll
    for (int m = 0; m < 4; ++m)
      #pragma unroll
      for (int r4 = 0; r4 < 4; ++r4) {
        int rowg = bx * 128 + wm * 64 + m * 16 + lkh * 4 + r4;
        gi[(size_t)rowg * 4608 + j] = f2bf(acc[m][n][r4] + bias);
      }
  }
}

// -------- persistent GRU recurrence: dense prefix GEMM + gates per step -----
// 192 blocks = 8 XCD x 3 ct x 8 bx; 512 thr (8 waves 4m x 2n);
// BM=128 BN=64 BK=64, double-buffered LDS; sorted order => NO gathers;
// gi packed per step => coalesced gates; relaxed-spin grid barrier.
__global__ __launch_bounds__(512, 4) void gh_persist_kernel(
    u16* __restrict__ hb0, u16* __restrict__ hb1,
    const u16* __restrict__ whh_bf, const u16* __restrict__ gi,
    const float* __restrict__ b_hh,
    const int* __restrict__ cnt_arr, const int* __restrict__ tstart,
    int* __restrict__ bar)
{
  int bid = blockIdx.x;
  int x8 = bid & 7, jj = bid >> 3;
  int ct = x8 * 3 + jj % 3;             // col tile 0..23, XCD-pinned
  int bx = jj / 3;                      // row tile 0..7
  __shared__ u16 lds[2 * 20480];        // 2 x 40 KB: [A 16K | Wr 8K | Wz 8K | Wn 8K]
  char* ldsb = (char*)lds;

  int tid = threadIdx.x, wid = tid >> 6, lane = tid & 63;
  int wm = wid >> 1, wn = wid & 1;
  int lrow = lane & 15, lkh = lane >> 4;

  for (int t = 0; t < LMAX; ++t) {
    const u16* h_cur = (t & 1) ? hb1 : hb0;
    u16*       h_nxt = (t & 1) ? hb0 : hb1;
    int cnt = cnt_arr[t];

    if (bx * 128 < cnt) {
      int ts = tstart[t];
      f32x4 acc[3][2][2] = {};

      auto STAGE = [&](int buf, int kt){
        int k0 = kt * 64;
        char* base = ldsb + buf * 40960;
        #pragma unroll
        for (int it = 0; it < 5; ++it) {
          int cb = it * 512 + wid * 64;
          int c  = cb + lane;
          const u16* src;
          if (c < 1024) {               // A: h prefix rows (dense)
            int row = c >> 3, slot = c & 7;
            int ridx = bx * 128 + row; if (ridx >= cnt) ridx = cnt - 1;
            src = h_cur + (size_t)ridx * H_DIM + k0 + ((slot ^ (row & 7)) << 3);
          } else {                      // W slabs
            int w = c - 1024;
            int slab = w >> 9, row = (w >> 3) & 63, slot = w & 7;
            src = whh_bf + (size_t)(slab * H_DIM + ct * 64 + row) * H_DIM
                  + k0 + ((slot ^ (row & 7)) << 3);
          }
          gload_lds16(src, base + (size_t)cb * 16);
        }
      };

      auto COMPUTE = [&](int buf){
        char* base = ldsb + buf * 40960;
        #pragma unroll
        for (int qq = 0; qq < 2; ++qq) {
          short8 ah[2], bw[3][2];
          int slot = qq * 4 + lkh;
          #pragma unroll
          for (int m = 0; m < 2; ++m) {
            int row = wm * 32 + m * 16 + lrow;
            ah[m] = *(const short8*)(base + row * 128 + ((slot ^ (row & 7)) << 4));
          }
          #pragma unroll
          for (int n = 0; n < 2; ++n) {
            int row = wn * 32 + n * 16 + lrow;
            int byte = row * 128 + ((slot ^ (row & 7)) << 4);
            #pragma unroll
            for (int s = 0; s < 3; ++s)
              bw[s][n] = *(const short8*)(base + 16384 + s * 8192 + byte);
          }
          #pragma unroll
          for (int s = 0; s < 3; ++s)
            #pragma unroll
            for (int m = 0; m < 2; ++m)
              #pragma unroll
              for (int n = 0; n < 2; ++n)
                acc[s][m][n] = __builtin_amdgcn_mfma_f32_16x16x32_bf16(
                    ah[m], bw[s][n], acc[s][m][n], 0, 0, 0);
        }
      };

      STAGE(0, 0);
      __syncthreads();
      int cur = 0;
      for (int kt = 0; kt < 24; ++kt) {
        if (kt + 1 < 24) STAGE(cur ^ 1, kt + 1);
        COMPUTE(cur);
        __syncthreads();
        cur ^= 1;
      }

      // gates — gi rows are packed & contiguous: row = ts + ridx
      #pragma unroll
      for (int n = 0; n < 2; ++n) {
        int lc = wn * 32 + n * 16 + lrow;
        int j = ct * 64 + lc;
        float bhr = b_hh[j], bhz = b_hh[H_DIM + j], bhn = b_hh[2*H_DIM + j];
        #pragma unroll
        for (int m = 0; m < 2; ++m)
          #pragma unroll
          for (int r4 = 0; r4 < 4; ++r4) {
            int lm = wm * 32 + m * 16 + lkh * 4 + r4;
            int ridx = bx * 128 + lm;
            if (ridx < cnt) {
              size_t gr = (size_t)(ts + ridx) * 4608;
              float gir = bf2f(gi[gr + j]);
              float giz = bf2f(gi[gr + H_DIM + j]);
              float gin = bf2f(gi[gr + 2*H_DIM + j]);
              float rr = sigm(gir + acc[0][m][n][r4] + bhr);
              float zz = sigm(giz + acc[1][m][n][r4] + bhz);
              float nn = tanhf(gin + rr * (acc[2][m][n][r4] + bhn));
              size_t hidx = (size_t)ridx * H_DIM + j;
              float hold = bf2f(h_cur[hidx]);
              h_nxt[hidx] = f2bf((1.f - zz) * nn + zz * hold);
            }
          }
      }
    }

    // ---- grid barrier: release add, RELAXED spin, one acquire fence ----
    if (t + 1 < LMAX) {
      __syncthreads();
      if (tid == 0) {
        __hip_atomic_fetch_add(bar, 1, __ATOMIC_RELEASE, __HIP_MEMORY_SCOPE_AGENT);
        int target = GH_BLOCKS * (t + 1);
        int guard = 0;
        while (__hip_atomic_load(bar, __ATOMIC_RELAXED, __HIP_MEMORY_SCOPE_AGENT) < target
               && ++guard < 100000000)
          __builtin_amdgcn_s_sleep(2);
      }
      __syncthreads();
      __builtin_amdgcn_fence(__ATOMIC_ACQUIRE, "agent");
    }
  }
}

// ---------------- scores: (h_final/T) @ k^T (gather by rank) ----------------
__global__ __launch_bounds__(256, 2) void scores_kernel(
    const u16* __restrict__ h0, const u16* __restrict__ h1,
    const int* __restrict__ lens, const int* __restrict__ rank,
    const u16* __restrict__ k_bf, float* __restrict__ scores)
{
  int bx = blockIdx.x, by = blockIdx.y;
  __shared__ u16 lds[2 * 64 * 64];
  char* ldsb = (char*)lds;
  int tid = threadIdx.x, wid = tid >> 6, lane = tid & 63;
  int wm = wid >> 1, wn = wid & 1;
  int lrow = lane & 15, lkh = lane >> 4;
  f32x4 acc[2][2] = {};

  for (int kt = 0; kt < 24; ++kt) {
    int k0 = kt * 64;
    #pragma unroll
    for (int it = 0; it < 4; ++it) {
      int cb = it * 256 + wid * 64;
      int c  = cb + lane;
      int isB = c >> 9;
      int cc  = c & 511;
      int row = cc >> 3, slot = cc & 7;
      const u16* src;
      if (!isB) {
        int g = bx * 64 + row;
        src = ((lens[g] & 1) ? h1 : h0) + (size_t)rank[g] * H_DIM;
      } else {
        src = k_bf + (size_t)(by * 64 + row) * H_DIM;
      }
      src += k0 + ((slot ^ (row & 7)) << 3);
      gload_lds16(src, ldsb + (size_t)cb * 16);
    }
    __syncthreads();
    #pragma unroll
    for (int qq = 0; qq < 2; ++qq) {
      short8 a[2], b[2];
      int slot = qq * 4 + lkh;
      #pragma unroll
      for (int m = 0; m < 2; ++m) {
        int row = wm * 32 + m * 16 + lrow;
        a[m] = *(const short8*)(ldsb + row * 128 + ((slot ^ (row & 7)) << 4));
      }
      #pragma unroll
      for (int n = 0; n < 2; ++n) {
        int row = wn * 32 + n * 16 + lrow;
        b[n] = *(const short8*)(ldsb + 8192 + row * 128 + ((slot ^ (row & 7)) << 4));
      }
      #pragma unroll
      for (int m = 0; m < 2; ++m)
        #pragma unroll
        for (int n = 0; n < 2; ++n)
          acc[m][n] = __builtin_amdgcn_mfma_f32_16x16x32_bf16(a[m], b[n], acc[m][n], 0,0,0);
    }
    __syncthreads();
  }
  #pragma unroll
  for (int m = 0; m < 2; ++m)
    #pragma unroll
    for (int n = 0; n < 2; ++n) {
      int col = by * 64 + wn * 32 + n * 16 + lrow;
      #pragma unroll
      for (int r4 = 0; r4 < 4; ++r4) {
        int rowg = bx * 64 + wm * 32 + m * 16 + lkh * 4 + r4;
        scores[(size_t)rowg * B_SZ + col] = acc[m][n][r4] * TEMP_INV;
      }
    }
}

// ---------------- per-row logsumexp loss ----------------
__global__ void softmax_kernel(const float* __restrict__ scores, float* __restrict__ row_loss){
  int i = blockIdx.x;
  int tid = threadIdx.x;
  const float* row = scores + (size_t)i * B_SZ;
  __shared__ float red[4];
  float m = -INFINITY;
  for (int j = tid; j < B_SZ; j += 256) m = fmaxf(m, row[j]);
  for (int off = 32; off; off >>= 1) m = fmaxf(m, __shfl_xor(m, off));
  if ((tid & 63) == 0) red[tid >> 6] = m;
  __syncthreads();
  m = fmaxf(fmaxf(red[0], red[1]), fmaxf(red[2], red[3]));
  __syncthreads();
  float s = 0.f;
  for (int j = tid; j < B_SZ; j += 256) s += __expf(row[j] - m);
  for (int off = 32; off; off >>= 1) s += __shfl_xor(s, off);
  if ((tid & 63) == 0) red[tid >> 6] = s;
  __syncthreads();
  if (tid == 0) {
    float S = red[0] + red[1] + red[2] + red[3];
    row_loss[i] = m + __logf(S) - row[i];
  }
}

__global__ void final_kernel(const float* __restrict__ row_loss, float* __restrict__ out){
  __shared__ float s[B_SZ];
  int i = threadIdx.x;
  s[i] = row_loss[i]; __syncthreads();
  for (int off = 512; off; off >>= 1) {
    if (i < off) s[i] += s[i + off];
    __syncthreads();
  }
  if (i == 0) out[0] = s[0] * (1.0f / B_SZ);
}

// ---------------- launch ----------------
extern "C" void kernel_launch(void* const* d_in, const int* in_sizes, int n_in,
                              void* d_out, int out_size, void* d_ws, size_t ws_size,
                              hipStream_t stream) {
  const float* q_emb = (const float*)d_in[0];
  const float* k_emb = (const float*)d_in[1];
  const float* inpn  = (const float*)d_in[2];
  const int*   lens  = (const int*)d_in[3];
  const float* wih   = (const float*)d_in[4];
  const float* whh   = (const float*)d_in[5];
  const float* bih   = (const float*)d_in[6];
  const float* bhh   = (const float*)d_in[7];
  float* out = (float*)d_out;

  int total  = in_sizes[2] / H_DIM;
  int mtiles = (total + 127) / 128;
  int Mpad   = mtiles * 128;

  char* p = (char*)d_ws;
  auto alloc = [&](size_t bytes){ char* r = p; p += (bytes + 255) & ~(size_t)255; return r; };
  int* rank      = (int*)alloc(B_SZ * 4);
  int* cnt_arr   = (int*)alloc(LMAX * 4);
  int* tstart    = (int*)alloc(LMAX * 4);
  int* bar       = (int*)alloc(256);
  int* rowmap    = (int*)alloc((size_t)Mpad * 4);
  u16* hbuf0     = (u16*)alloc((size_t)B_SZ * H_DIM * 2);
  u16* hbuf1     = (u16*)alloc((size_t)B_SZ * H_DIM * 2);
  u16* wih_bf    = (u16*)alloc((size_t)H3 * H_DIM * 2);
  u16* whh_bf    = (u16*)alloc((size_t)H3 * H_DIM * 2);
  u16* k_bf      = (u16*)alloc((size_t)B_SZ * H_DIM * 2);
  u16* xt        = (u16*)alloc((size_t)Mpad * H_DIM * 2);
  u16* gi        = (u16*)alloc((size_t)Mpad * H3 * 2);
  float* scores  = (float*)alloc((size_t)B_SZ * B_SZ * 4);
  float* row_loss= (float*)alloc(B_SZ * 4);
  if ((size_t)(p - (char*)d_ws) > ws_size) return;  // workspace too small (loud fail)

  hipMemsetAsync(bar, 0, 256, stream);

  sort_kernel<<<1, B_SZ, 0, stream>>>(lens, rank, cnt_arr, tstart, rowmap);
  prep_kernel<<<(H3 * H_DIM / 8) / 256, 256, 0, stream>>>(
      wih, whh, k_emb, q_emb, rank, wih_bf, whh_bf, k_bf, hbuf0);
  convx_kernel<<<((size_t)Mpad * H_DIM / 8) / 256, 256, 0, stream>>>(
      inpn, rowmap, xt, total);

  gi_gemm_kernel<<<mtiles * 36, 256, 0, stream>>>(xt, wih_bf, bih, gi, mtiles);

  gh_persist_kernel<<<GH_BLOCKS, 512, 0, stream>>>(
      hbuf0, hbuf1, whh_bf, gi, bhh, cnt_arr, tstart, bar);

  scores_kernel<<<dim3(B_SZ / 64, B_SZ / 64), 256, 0, stream>>>(
      hbuf0, hbuf1, lens, rank, k_bf, scores);
  softmax_kernel<<<B_SZ, 256, 0, stream>>>(scores, row_loss);
  final_kernel<<<1, B_SZ, 0, stream>>>(row_loss, out);
}